// Round 17
// baseline (108.170 us; speedup 1.0000x reference)
//
#include <hip/hip_runtime.h>
#include <hip/hip_bf16.h>

// Problem dims (fixed by the reference)
#define NTOK   (256 * 512)     // B*S tokens
#define N_USER 7442

using bf16 = __hip_bfloat16;
typedef float f32x4 __attribute__((ext_vector_type(4)));  // native vec for nontemporal builtin

static __device__ __forceinline__ float4 ld4(const float* p) {
    return *reinterpret_cast<const float4*>(p);
}
static __device__ __forceinline__ float bfl(unsigned u) {
    union { unsigned u; float f; } c; c.u = u << 16; return c.f;
}
static __device__ __forceinline__ float bfh(unsigned u) {
    union { unsigned u; float f; } c; c.u = u & 0xFFFF0000u; return c.f;
}
// NT store (round-15 A/B: NT beats normal stores by ~16 us here — protects L2 for gathers)
static __device__ __forceinline__ void st_nt4(float* p, float x, float y, float z, float w) {
    f32x4 v; v.x = x; v.y = y; v.z = z; v.w = w;
    __builtin_nontemporal_store(v, reinterpret_cast<f32x4*>(p));
}
static __device__ __forceinline__ float rnd_bf(float x) {   // round f32 -> bf16 -> f32
    return __bfloat162float(__float2bfloat16(x));
}
static __device__ __forceinline__ void st_bf4(bf16* dst, float4 v) {
    union { bf16 h[4]; uint2 u; } pk;
    pk.h[0] = __float2bfloat16(v.x);
    pk.h[1] = __float2bfloat16(v.y);
    pk.h[2] = __float2bfloat16(v.z);
    pk.h[3] = __float2bfloat16(v.w);
    *reinterpret_cast<uint2*>(dst) = pk.u;
}

// Wave64 sum via DPP (pure VALU); result broadcast to all lanes via readlane.
template <int CTRL, int ROW_MASK>
static __device__ __forceinline__ float dpp_add(float x) {
    const int sh = __builtin_amdgcn_update_dpp(0, __float_as_int(x), CTRL, ROW_MASK, 0xf, true);
    return x + __int_as_float(sh);
}
static __device__ __forceinline__ float wave_sum(float x) {
    x = dpp_add<0x111, 0xf>(x);
    x = dpp_add<0x112, 0xf>(x);
    x = dpp_add<0x114, 0xf>(x);
    x = dpp_add<0x118, 0xf>(x);
    x = dpp_add<0x142, 0xa>(x);
    x = dpp_add<0x143, 0xc>(x);
    return __int_as_float(__builtin_amdgcn_readlane(__float_as_int(x), 63));
}
static __device__ __forceinline__ float dot4(float4 a, float4 b) {
    return a.x * b.x + a.y * b.y + a.z * b.z + a.w * b.w;
}

// ---- kernel A geometry: 128-thread (2-wave) blocks, K-split precompute ----
// LDS shrunk to 16 KB (graph path: 4 rows/block) -> 10 blocks/CU (~5 waves/SIMD),
// up from 6 blocks/CU at 25.6 KB. W-read-once-per-block preserved.
#define NB_TESTG 375          // 1500/4, 4 rows/block (exact, no tail)
#define NB_ITEM  591          // ceil(9455/16), 16 rows/block
#define NB_TAG   58           // ceil(913/16)
#define NB_INT   1
#define NB_PC    (NB_TESTG + NB_ITEM + NB_TAG + NB_INT)   // 1025
#define NB_CONT  4096         // 2 waves x 16 tokens each -> 8192 waves
#define NB_A     (NB_PC + NB_CONT)

__global__ __launch_bounds__(128) void precompute_cont_kernel(
    const float* __restrict__ emb_int,  const float* __restrict__ emb_test,
    const float* __restrict__ emb_item, const float* __restrict__ emb_tag,
    const float* __restrict__ graph_tab, const float* __restrict__ graph_W,
    const float* __restrict__ graph_b,
    const float* __restrict__ comb_W,   const float* __restrict__ comb_b,
    const float* __restrict__ cont_feats,
    const float* __restrict__ cont_W,   const float* __restrict__ cont_b,
    const float* __restrict__ cont_g,   const float* __restrict__ cont_beta,
    bf16* __restrict__ Pint, bf16* __restrict__ Ptestg,
    bf16* __restrict__ Pitem, bf16* __restrict__ Ptag,
    float* __restrict__ Rint, float* __restrict__ Rtestg,
    float* __restrict__ Ritem, float* __restrict__ Rtag,
    float* __restrict__ out) {
    __shared__ float lds[4096];   // 16 KB
    const int tid  = threadIdx.x;
    const int w    = tid >> 6;    // 0 or 1
    const int lane = tid & 63;
    const int c    = lane * 4;
    const int b    = blockIdx.x;

    if (b >= NB_PC) {
        // ================= cont-writer block: 2 waves x 16 tokens =================
        const float4 w0  = ld4(cont_W + 0 * 256 + c);
        const float4 w1  = ld4(cont_W + 1 * 256 + c);
        const float4 w2  = ld4(cont_W + 2 * 256 + c);
        const float4 cb  = ld4(cont_b + c);
        const float4 g42 = ld4(cont_g + c);
        const float4 b42 = ld4(cont_beta + c);

        const float inv256 = 1.f / 256.f;
        const float M0  = wave_sum(w0.x + w0.y + w0.z + w0.w) * inv256;
        const float M1  = wave_sum(w1.x + w1.y + w1.z + w1.w) * inv256;
        const float M2  = wave_sum(w2.x + w2.y + w2.z + w2.w) * inv256;
        const float M3  = wave_sum(cb.x + cb.y + cb.z + cb.w) * inv256;
        const float P00 = wave_sum(dot4(w0, w0)) * inv256;
        const float P11 = wave_sum(dot4(w1, w1)) * inv256;
        const float P22 = wave_sum(dot4(w2, w2)) * inv256;
        const float P33 = wave_sum(dot4(cb, cb)) * inv256;
        const float P01 = wave_sum(dot4(w0, w1)) * inv256;
        const float P02 = wave_sum(dot4(w0, w2)) * inv256;
        const float P12 = wave_sum(dot4(w1, w2)) * inv256;
        const float P03 = wave_sum(dot4(w0, cb)) * inv256;
        const float P13 = wave_sum(dot4(w1, cb)) * inv256;
        const float P23 = wave_sum(dot4(w2, cb)) * inv256;

        const int wid = (b - NB_PC) * 2 + w;
        const int t0  = wid * 16;
        for (int k4 = 0; k4 < 4; ++k4) {
            const int tb = t0 + k4 * 4;
            const float4 cf0 = ld4(cont_feats + (size_t)tb * 3);
            const float4 cf1 = ld4(cont_feats + (size_t)tb * 3 + 4);
            const float4 cf2 = ld4(cont_feats + (size_t)tb * 3 + 8);
            const float cf[12] = {cf0.x, cf0.y, cf0.z, cf0.w,
                                  cf1.x, cf1.y, cf1.z, cf1.w,
                                  cf2.x, cf2.y, cf2.z, cf2.w};
            #pragma unroll
            for (int j = 0; j < 4; ++j) {
                const int t = tb + j;
                const float c0 = cf[j * 3 + 0];
                const float c1 = cf[j * 3 + 1];
                const float c2 = cf[j * 3 + 2];
                const float mu2 = c0 * M0 + c1 * M1 + c2 * M2 + M3;
                const float e2  = c0 * c0 * P00 + c1 * c1 * P11 + c2 * c2 * P22 + P33
                                + 2.f * (c0 * c1 * P01 + c0 * c2 * P02 + c1 * c2 * P12
                                       + c0 * P03 + c1 * P13 + c2 * P23);
                const float inv2 = rsqrtf(e2 - mu2 * mu2 + 1e-5f);

                const float ux = c0 * w0.x + c1 * w1.x + c2 * w2.x + cb.x;
                const float uy = c0 * w0.y + c1 * w1.y + c2 * w2.y + cb.y;
                const float uz = c0 * w0.z + c1 * w1.z + c2 * w2.z + cb.z;
                const float uw = c0 * w0.w + c1 * w1.w + c2 * w2.w + cb.w;

                st_nt4(out + (size_t)t * 512 + 256 + c,
                       (ux - mu2) * inv2 * g42.x + b42.x,
                       (uy - mu2) * inv2 * g42.y + b42.y,
                       (uz - mu2) * inv2 * g42.z + b42.z,
                       (uw - mu2) * inv2 * g42.w + b42.w);
            }
        }
        return;
    }

    const float* W0 = comb_W;
    const float* W1 = comb_W + 256 * 256;
    const float* W2 = comb_W + 512 * 256;
    const float* W3 = comb_W + 768 * 256;
    const float* W4 = comb_W + 1024 * 256;

    if (b < NB_TESTG) {
        // ============ graph+test fused path: 4 rows, 2-wave K-split, 16 KB ============
        const int row0 = b * 4;   // nr == 4 always (1500 = 375*4)

        // A: stage G[4][512] at lds[0..2048)
        for (int i = tid; i < 512; i += 128) {
            const int r = i >> 7, m4 = (i & 127) * 4;
            *reinterpret_cast<float4*>(&lds[r * 512 + m4]) =
                ld4(graph_tab + (size_t)(N_USER - 1 + row0 + r) * 512 + m4);
        }
        __syncthreads();

        // B: tmp = G @ graph_W, wave k-slice [w*256, +256)
        float4 acc[4];
        #pragma unroll
        for (int r = 0; r < 4; ++r) acc[r] = float4{0.f, 0.f, 0.f, 0.f};
        for (int m = w * 256; m < w * 256 + 256; m += 4) {
            const float4 wv0 = ld4(graph_W + (m + 0) * 256 + c);
            const float4 wv1 = ld4(graph_W + (m + 1) * 256 + c);
            const float4 wv2 = ld4(graph_W + (m + 2) * 256 + c);
            const float4 wv3 = ld4(graph_W + (m + 3) * 256 + c);
            #pragma unroll
            for (int r = 0; r < 4; ++r) {
                const float4 e = ld4(&lds[r * 512 + m]);
                acc[r].x += e.x * wv0.x + e.y * wv1.x + e.z * wv2.x + e.w * wv3.x;
                acc[r].y += e.x * wv0.y + e.y * wv1.y + e.z * wv2.y + e.w * wv3.y;
                acc[r].z += e.x * wv0.z + e.y * wv1.z + e.z * wv2.z + e.w * wv3.z;
                acc[r].w += e.x * wv0.w + e.y * wv1.w + e.z * wv2.w + e.w * wv3.w;
            }
        }
        __syncthreads();   // G reads done

        // reduce tmp into lds[2048..3072)
        if (w == 0) {
            #pragma unroll
            for (int r = 0; r < 4; ++r)
                *reinterpret_cast<float4*>(&lds[2048 + r * 256 + c]) = acc[r];
        }
        __syncthreads();
        if (w == 1) {
            #pragma unroll
            for (int r = 0; r < 4; ++r) {
                float4 t = ld4(&lds[2048 + r * 256 + c]);
                t.x += acc[r].x; t.y += acc[r].y; t.z += acc[r].z; t.w += acc[r].w;
                *reinterpret_cast<float4*>(&lds[2048 + r * 256 + c]) = t;
            }
        }
        // stage emb_test[4][256] at lds[3072..4096) (disjoint from tmp reduce)
        for (int i = tid; i < 256; i += 128) {
            const int r = i >> 6, m4 = (i & 63) * 4;
            *reinterpret_cast<float4*>(&lds[3072 + r * 256 + m4]) =
                ld4(emb_test + (size_t)(row0 + r) * 256 + m4);
        }
        __syncthreads();

        // C: P = tmp @ W4 + test @ W1 + bias, wave k-slice [w*128, +128)
        float4 acc2[4];
        float4 bacc = float4{0.f, 0.f, 0.f, 0.f};
        #pragma unroll
        for (int r = 0; r < 4; ++r) acc2[r] = float4{0.f, 0.f, 0.f, 0.f};
        for (int m = w * 128; m < w * 128 + 128; m += 4) {
            const float4 w40 = ld4(W4 + (m + 0) * 256 + c);
            const float4 w41 = ld4(W4 + (m + 1) * 256 + c);
            const float4 w42 = ld4(W4 + (m + 2) * 256 + c);
            const float4 w43 = ld4(W4 + (m + 3) * 256 + c);
            const float4 w10 = ld4(W1 + (m + 0) * 256 + c);
            const float4 w11 = ld4(W1 + (m + 1) * 256 + c);
            const float4 w12 = ld4(W1 + (m + 2) * 256 + c);
            const float4 w13 = ld4(W1 + (m + 3) * 256 + c);
            const float gb0 = graph_b[m + 0], gb1 = graph_b[m + 1];
            const float gb2 = graph_b[m + 2], gb3 = graph_b[m + 3];
            bacc.x += gb0 * w40.x + gb1 * w41.x + gb2 * w42.x + gb3 * w43.x;
            bacc.y += gb0 * w40.y + gb1 * w41.y + gb2 * w42.y + gb3 * w43.y;
            bacc.z += gb0 * w40.z + gb1 * w41.z + gb2 * w42.z + gb3 * w43.z;
            bacc.w += gb0 * w40.w + gb1 * w41.w + gb2 * w42.w + gb3 * w43.w;
            #pragma unroll
            for (int r = 0; r < 4; ++r) {
                const float4 tv = ld4(&lds[2048 + r * 256 + m]);
                const float4 ev = ld4(&lds[3072 + r * 256 + m]);
                acc2[r].x += tv.x * w40.x + tv.y * w41.x + tv.z * w42.x + tv.w * w43.x
                           + ev.x * w10.x + ev.y * w11.x + ev.z * w12.x + ev.w * w13.x;
                acc2[r].y += tv.x * w40.y + tv.y * w41.y + tv.z * w42.y + tv.w * w43.y
                           + ev.x * w10.y + ev.y * w11.y + ev.z * w12.y + ev.w * w13.y;
                acc2[r].z += tv.x * w40.z + tv.y * w41.z + tv.z * w42.z + tv.w * w43.z
                           + ev.x * w10.z + ev.y * w11.z + ev.z * w12.z + ev.w * w13.z;
                acc2[r].w += tv.x * w40.w + tv.y * w41.w + tv.z * w42.w + tv.w * w43.w
                           + ev.x * w10.w + ev.y * w11.w + ev.z * w12.w + ev.w * w13.w;
            }
        }
        __syncthreads();   // tmp/test reads done

        // reduce acc2 -> lds[0..1024) (G dead), bacc -> lds[1024..1280)
        if (w == 0) {
            #pragma unroll
            for (int r = 0; r < 4; ++r)
                *reinterpret_cast<float4*>(&lds[r * 256 + c]) = acc2[r];
            *reinterpret_cast<float4*>(&lds[1024 + c]) = bacc;
        }
        __syncthreads();
        if (w == 1) {
            #pragma unroll
            for (int r = 0; r < 4; ++r) {
                float4 t = ld4(&lds[r * 256 + c]);
                t.x += acc2[r].x; t.y += acc2[r].y; t.z += acc2[r].z; t.w += acc2[r].w;
                *reinterpret_cast<float4*>(&lds[r * 256 + c]) = t;
            }
            float4 t = ld4(&lds[1024 + c]);
            t.x += bacc.x; t.y += bacc.y; t.z += bacc.z; t.w += bacc.w;
            *reinterpret_cast<float4*>(&lds[1024 + c]) = t;
        }
        __syncthreads();

        // final: wave w stores rows w*2 .. w*2+1
        const float4 cbv = ld4(comb_b + c);
        const float4 bb  = ld4(&lds[1024 + c]);
        #pragma unroll
        for (int r4 = 0; r4 < 2; ++r4) {
            const int r = w * 2 + r4;
            float4 o = ld4(&lds[r * 256 + c]);
            o.x += bb.x + cbv.x;
            o.y += bb.y + cbv.y;
            o.z += bb.z + cbv.z;
            o.w += bb.w + cbv.w;
            const float rs = wave_sum(rnd_bf(o.x) + rnd_bf(o.y) + rnd_bf(o.z) + rnd_bf(o.w));
            st_bf4(Ptestg + (size_t)(row0 + r) * 256 + c, o);
            if (lane == 0) Rtestg[row0 + r] = rs;
        }
    } else {
        // ============ simple path: P = E @ W, 16 rows, 2-wave K-split (16 KB) ============
        const float* E; const float* W; bf16* P; float* R; int row0, Rn;
        const int sb = b - NB_TESTG;
        if (sb < NB_ITEM)               { E = emb_item; W = W2; P = Pitem; R = Ritem; row0 = sb * 16;             Rn = 9455; }
        else if (sb < NB_ITEM + NB_TAG) { E = emb_tag;  W = W3; P = Ptag;  R = Rtag;  row0 = (sb - NB_ITEM) * 16; Rn = 913;  }
        else                            { E = emb_int;  W = W0; P = Pint;  R = Rint;  row0 = 0;                   Rn = 3;    }
        const int nr = min(16, Rn - row0);

        for (int i = tid; i < 1024; i += 128) {
            const int r = i >> 6, m4 = (i & 63) * 4;
            const int rr = min(r, nr - 1);
            *reinterpret_cast<float4*>(&lds[r * 256 + m4]) =
                ld4(E + (size_t)(row0 + rr) * 256 + m4);
        }
        __syncthreads();

        float4 acc[16];
        #pragma unroll
        for (int r = 0; r < 16; ++r) acc[r] = float4{0.f, 0.f, 0.f, 0.f};
        for (int m = w * 128; m < w * 128 + 128; m += 4) {
            const float4 wv0 = ld4(W + (m + 0) * 256 + c);
            const float4 wv1 = ld4(W + (m + 1) * 256 + c);
            const float4 wv2 = ld4(W + (m + 2) * 256 + c);
            const float4 wv3 = ld4(W + (m + 3) * 256 + c);
            #pragma unroll
            for (int r = 0; r < 16; ++r) {
                const float4 e = ld4(&lds[r * 256 + m]);
                acc[r].x += e.x * wv0.x + e.y * wv1.x + e.z * wv2.x + e.w * wv3.x;
                acc[r].y += e.x * wv0.y + e.y * wv1.y + e.z * wv2.y + e.w * wv3.y;
                acc[r].z += e.x * wv0.z + e.y * wv1.z + e.z * wv2.z + e.w * wv3.z;
                acc[r].w += e.x * wv0.w + e.y * wv1.w + e.z * wv2.w + e.w * wv3.w;
            }
        }
        __syncthreads();   // E reads done before overwrite

        if (w == 0) {
            #pragma unroll
            for (int r = 0; r < 16; ++r)
                *reinterpret_cast<float4*>(&lds[r * 256 + c]) = acc[r];
        }
        __syncthreads();
        if (w == 1) {
            #pragma unroll
            for (int r = 0; r < 16; ++r) {
                float4 t = ld4(&lds[r * 256 + c]);
                t.x += acc[r].x; t.y += acc[r].y; t.z += acc[r].z; t.w += acc[r].w;
                *reinterpret_cast<float4*>(&lds[r * 256 + c]) = t;
            }
        }
        __syncthreads();

        #pragma unroll
        for (int r8 = 0; r8 < 8; ++r8) {
            const int r = w * 8 + r8;
            const float4 o = ld4(&lds[r * 256 + c]);
            const float rs = wave_sum(rnd_bf(o.x) + rnd_bf(o.y) + rnd_bf(o.z) + rnd_bf(o.w));
            if (r < nr) {
                st_bf4(P + (size_t)(row0 + r) * 256 + c, o);
                if (lane == 0) R[row0 + r] = rs;
            }
        }
    }
}

// Kernel B: cate half only. 8192 blocks x 4 waves x 4 tokens (round-13 proven form).
__global__ __launch_bounds__(256) void main_cate_kernel(
    const int* __restrict__ testId, const int* __restrict__ itemId,
    const int* __restrict__ tagId,  const int* __restrict__ inter,
    const bf16* __restrict__ Pint, const bf16* __restrict__ Ptestg,
    const bf16* __restrict__ Pitem, const bf16* __restrict__ Ptag,
    const float* __restrict__ Rint, const float* __restrict__ Rtestg,
    const float* __restrict__ Ritem, const float* __restrict__ Rtag,
    const float* __restrict__ comb_g, const float* __restrict__ comb_beta,
    float* __restrict__ out) {
    const int wid  = blockIdx.x * 4 + (threadIdx.x >> 6);
    const int lane = threadIdx.x & 63;
    const int c    = lane * 4;

    const float4 g4 = ld4(comb_g + c);
    const float4 b4 = ld4(comb_beta + c);
    const uint2 p0 = *reinterpret_cast<const uint2*>(Pint + 0 * 256 + c);
    const uint2 p1 = *reinterpret_cast<const uint2*>(Pint + 1 * 256 + c);
    const uint2 p2 = *reinterpret_cast<const uint2*>(Pint + 2 * 256 + c);
    const float ri0 = Rint[0], ri1 = Rint[1], ri2 = Rint[2];

    const int tb = wid * 4;
    const int4 tiv = *reinterpret_cast<const int4*>(testId + tb);
    const int4 iiv = *reinterpret_cast<const int4*>(itemId + tb);
    const int4 tgv = *reinterpret_cast<const int4*>(tagId  + tb);
    const int4 ivv = *reinterpret_cast<const int4*>(inter  + tb);
    const int tis[4] = {tiv.x, tiv.y, tiv.z, tiv.w};
    const int iis[4] = {iiv.x, iiv.y, iiv.z, iiv.w};
    const int tgs[4] = {tgv.x, tgv.y, tgv.z, tgv.w};
    const int ivs[4] = {ivv.x, ivv.y, ivv.z, ivv.w};

    uint2 gT[4], gI[4], gG[4];
    float sT[4], sI[4], sG[4];
    #pragma unroll
    for (int j = 0; j < 4; ++j) {
        gT[j] = *reinterpret_cast<const uint2*>(Ptestg + (size_t)tis[j] * 256 + c);
        gI[j] = *reinterpret_cast<const uint2*>(Pitem  + (size_t)iis[j] * 256 + c);
        gG[j] = *reinterpret_cast<const uint2*>(Ptag   + (size_t)tgs[j] * 256 + c);
        sT[j] = Rtestg[tis[j]];
        sI[j] = Ritem[iis[j]];
        sG[j] = Rtag[tgs[j]];
    }

    #pragma unroll
    for (int j = 0; j < 4; ++j) {
        const int t = tb + j;

        uint2 u0;
        u0.x = ivs[j] == 0 ? p0.x : (ivs[j] == 1 ? p1.x : p2.x);
        u0.y = ivs[j] == 0 ? p0.y : (ivs[j] == 1 ? p1.y : p2.y);
        const float sInt = ivs[j] == 0 ? ri0 : (ivs[j] == 1 ? ri1 : ri2);

        const float vx = bfl(u0.x) + bfl(gT[j].x) + bfl(gI[j].x) + bfl(gG[j].x);
        const float vy = bfh(u0.x) + bfh(gT[j].x) + bfh(gI[j].x) + bfh(gG[j].x);
        const float vz = bfl(u0.y) + bfl(gT[j].y) + bfl(gI[j].y) + bfl(gG[j].y);
        const float vw = bfh(u0.y) + bfh(gT[j].y) + bfh(gI[j].y) + bfh(gG[j].y);

        const float s   = sInt + sT[j] + sI[j] + sG[j];          // separable mean
        const float ss  = wave_sum(vx * vx + vy * vy + vz * vz + vw * vw);
        const float mu  = s * (1.f / 256.f);
        const float var = ss * (1.f / 256.f) - mu * mu;
        const float inv = rsqrtf(var + 1e-5f);

        st_nt4(out + (size_t)t * 512 + c,
               (vx - mu) * inv * g4.x + b4.x,
               (vy - mu) * inv * g4.y + b4.y,
               (vz - mu) * inv * g4.z + b4.z,
               (vw - mu) * inv * g4.w + b4.w);
    }
}

extern "C" void kernel_launch(void* const* d_in, const int* in_sizes, int n_in,
                              void* d_out, int out_size, void* d_ws, size_t ws_size,
                              hipStream_t stream) {
    const int*   testId     = (const int*)d_in[0];
    const int*   itemId     = (const int*)d_in[1];
    const int*   tagId      = (const int*)d_in[2];
    const float* cont_feats = (const float*)d_in[3];
    const int*   inter      = (const int*)d_in[4];
    const float* emb_int    = (const float*)d_in[5];
    const float* emb_test   = (const float*)d_in[6];
    const float* emb_item   = (const float*)d_in[7];
    const float* emb_tag    = (const float*)d_in[8];
    const float* graph_tab  = (const float*)d_in[9];
    const float* graph_W    = (const float*)d_in[10];
    const float* graph_b    = (const float*)d_in[11];
    const float* comb_W     = (const float*)d_in[12];
    const float* comb_b     = (const float*)d_in[13];
    const float* comb_g     = (const float*)d_in[14];
    const float* comb_beta  = (const float*)d_in[15];
    const float* cont_W     = (const float*)d_in[16];
    const float* cont_b     = (const float*)d_in[17];
    const float* cont_g     = (const float*)d_in[18];
    const float* cont_beta  = (const float*)d_in[19];
    float* out              = (float*)d_out;

    // Workspace: bf16 tables (~6.08 MB) then f32 row-sums (~48 KB).
    bf16* ws     = (bf16*)d_ws;
    bf16* Pitem  = ws;                         // 9455*256
    bf16* Ptestg = Pitem  + 9455 * 256;        // 1500*256
    bf16* Ptag   = Ptestg + 1500 * 256;        //  913*256
    bf16* Pint   = Ptag   +  913 * 256;        //    3*256
    float* Ritem  = (float*)(Pint + 3 * 256);  // 9455
    float* Rtestg = Ritem  + 9455;             // 1500
    float* Rtag   = Rtestg + 1500;             //  913
    float* Rint   = Rtag   +  913;             //    3

    precompute_cont_kernel<<<NB_A, 128, 0, stream>>>(
        emb_int, emb_test, emb_item, emb_tag, graph_tab, graph_W, graph_b,
        comb_W, comb_b, cont_feats, cont_W, cont_b, cont_g, cont_beta,
        Pint, Ptestg, Pitem, Ptag,
        Rint, Rtestg, Ritem, Rtag, out);

    main_cate_kernel<<<NTOK / (4 * 4), 256, 0, stream>>>(
        testId, itemId, tagId, inter,
        Pint, Ptestg, Pitem, Ptag,
        Rint, Rtestg, Ritem, Rtag,
        comb_g, comb_beta, out);
}

// Round 18
// 103.917 us; speedup vs baseline: 1.0409x; 1.0409x over previous
//
#include <hip/hip_runtime.h>
#include <hip/hip_bf16.h>

// Problem dims (fixed by the reference)
#define NTOK   (256 * 512)     // B*S tokens
#define N_USER 7442

using bf16 = __hip_bfloat16;
typedef float f32x4 __attribute__((ext_vector_type(4)));  // native vec for nontemporal builtin

static __device__ __forceinline__ float4 ld4(const float* p) {
    return *reinterpret_cast<const float4*>(p);
}
static __device__ __forceinline__ float bfl(unsigned u) {
    union { unsigned u; float f; } c; c.u = u << 16; return c.f;
}
static __device__ __forceinline__ float bfh(unsigned u) {
    union { unsigned u; float f; } c; c.u = u & 0xFFFF0000u; return c.f;
}
// NT store (round-15 A/B: NT beats normal stores by ~16 us — protects L2 for gathers)
static __device__ __forceinline__ void st_nt4(float* p, float x, float y, float z, float w) {
    f32x4 v; v.x = x; v.y = y; v.z = z; v.w = w;
    __builtin_nontemporal_store(v, reinterpret_cast<f32x4*>(p));
}
static __device__ __forceinline__ float rnd_bf(float x) {   // round f32 -> bf16 -> f32
    return __bfloat162float(__float2bfloat16(x));
}
static __device__ __forceinline__ void st_bf4(bf16* dst, float4 v) {
    union { bf16 h[4]; uint2 u; } pk;
    pk.h[0] = __float2bfloat16(v.x);
    pk.h[1] = __float2bfloat16(v.y);
    pk.h[2] = __float2bfloat16(v.z);
    pk.h[3] = __float2bfloat16(v.w);
    *reinterpret_cast<uint2*>(dst) = pk.u;
}

// Wave64 sum via DPP (pure VALU); result broadcast to all lanes via readlane.
template <int CTRL, int ROW_MASK>
static __device__ __forceinline__ float dpp_add(float x) {
    const int sh = __builtin_amdgcn_update_dpp(0, __float_as_int(x), CTRL, ROW_MASK, 0xf, true);
    return x + __int_as_float(sh);
}
static __device__ __forceinline__ float wave_sum(float x) {
    x = dpp_add<0x111, 0xf>(x);
    x = dpp_add<0x112, 0xf>(x);
    x = dpp_add<0x114, 0xf>(x);
    x = dpp_add<0x118, 0xf>(x);
    x = dpp_add<0x142, 0xa>(x);
    x = dpp_add<0x143, 0xc>(x);
    return __int_as_float(__builtin_amdgcn_readlane(__float_as_int(x), 63));
}
static __device__ __forceinline__ float dot4(float4 a, float4 b) {
    return a.x * b.x + a.y * b.y + a.z * b.z + a.w * b.w;
}

// ---- kernel A geometry: 128-thread (2-wave) blocks, K-split precompute ----
// Round-13 proven optimum: 25.6 KB LDS, graph 8 rows/block, simple 16 rows/block.
// Each wave handles HALF the K range -> every W element read from L2 ONCE per
// block; partials reduced via LDS. Cont-writer blocks backfill CUs as
// precompute blocks drain (the overlap r14 proved is worth ~20 us).
#define NB_TESTG 188          // ceil(1500/8), 8 rows/block
#define NB_ITEM  591          // ceil(9455/16), 16 rows/block
#define NB_TAG   58           // ceil(913/16)
#define NB_INT   1
#define NB_PC    (NB_TESTG + NB_ITEM + NB_TAG + NB_INT)   // 838
#define NB_CONT  4096         // 2 waves x 16 tokens each -> 8192 waves
#define NB_A     (NB_PC + NB_CONT)

__global__ __launch_bounds__(128) void precompute_cont_kernel(
    const float* __restrict__ emb_int,  const float* __restrict__ emb_test,
    const float* __restrict__ emb_item, const float* __restrict__ emb_tag,
    const float* __restrict__ graph_tab, const float* __restrict__ graph_W,
    const float* __restrict__ graph_b,
    const float* __restrict__ comb_W,   const float* __restrict__ comb_b,
    const float* __restrict__ cont_feats,
    const float* __restrict__ cont_W,   const float* __restrict__ cont_b,
    const float* __restrict__ cont_g,   const float* __restrict__ cont_beta,
    bf16* __restrict__ Pint, bf16* __restrict__ Ptestg,
    bf16* __restrict__ Pitem, bf16* __restrict__ Ptag,
    float* __restrict__ Rint, float* __restrict__ Rtestg,
    float* __restrict__ Ritem, float* __restrict__ Rtag,
    float* __restrict__ out) {
    __shared__ float lds[6400];   // 25.6 KB
    const int tid  = threadIdx.x;
    const int w    = tid >> 6;    // 0 or 1
    const int lane = tid & 63;
    const int c    = lane * 4;
    const int b    = blockIdx.x;

    if (b >= NB_PC) {
        // ================= cont-writer block: 2 waves x 16 tokens =================
        const float4 w0  = ld4(cont_W + 0 * 256 + c);
        const float4 w1  = ld4(cont_W + 1 * 256 + c);
        const float4 w2  = ld4(cont_W + 2 * 256 + c);
        const float4 cb  = ld4(cont_b + c);
        const float4 g42 = ld4(cont_g + c);
        const float4 b42 = ld4(cont_beta + c);

        const float inv256 = 1.f / 256.f;
        const float M0  = wave_sum(w0.x + w0.y + w0.z + w0.w) * inv256;
        const float M1  = wave_sum(w1.x + w1.y + w1.z + w1.w) * inv256;
        const float M2  = wave_sum(w2.x + w2.y + w2.z + w2.w) * inv256;
        const float M3  = wave_sum(cb.x + cb.y + cb.z + cb.w) * inv256;
        const float P00 = wave_sum(dot4(w0, w0)) * inv256;
        const float P11 = wave_sum(dot4(w1, w1)) * inv256;
        const float P22 = wave_sum(dot4(w2, w2)) * inv256;
        const float P33 = wave_sum(dot4(cb, cb)) * inv256;
        const float P01 = wave_sum(dot4(w0, w1)) * inv256;
        const float P02 = wave_sum(dot4(w0, w2)) * inv256;
        const float P12 = wave_sum(dot4(w1, w2)) * inv256;
        const float P03 = wave_sum(dot4(w0, cb)) * inv256;
        const float P13 = wave_sum(dot4(w1, cb)) * inv256;
        const float P23 = wave_sum(dot4(w2, cb)) * inv256;

        const int wid = (b - NB_PC) * 2 + w;
        const int t0  = wid * 16;
        for (int k4 = 0; k4 < 4; ++k4) {
            const int tb = t0 + k4 * 4;
            const float4 cf0 = ld4(cont_feats + (size_t)tb * 3);
            const float4 cf1 = ld4(cont_feats + (size_t)tb * 3 + 4);
            const float4 cf2 = ld4(cont_feats + (size_t)tb * 3 + 8);
            const float cf[12] = {cf0.x, cf0.y, cf0.z, cf0.w,
                                  cf1.x, cf1.y, cf1.z, cf1.w,
                                  cf2.x, cf2.y, cf2.z, cf2.w};
            #pragma unroll
            for (int j = 0; j < 4; ++j) {
                const int t = tb + j;
                const float c0 = cf[j * 3 + 0];
                const float c1 = cf[j * 3 + 1];
                const float c2 = cf[j * 3 + 2];
                const float mu2 = c0 * M0 + c1 * M1 + c2 * M2 + M3;
                const float e2  = c0 * c0 * P00 + c1 * c1 * P11 + c2 * c2 * P22 + P33
                                + 2.f * (c0 * c1 * P01 + c0 * c2 * P02 + c1 * c2 * P12
                                       + c0 * P03 + c1 * P13 + c2 * P23);
                const float inv2 = rsqrtf(e2 - mu2 * mu2 + 1e-5f);

                const float ux = c0 * w0.x + c1 * w1.x + c2 * w2.x + cb.x;
                const float uy = c0 * w0.y + c1 * w1.y + c2 * w2.y + cb.y;
                const float uz = c0 * w0.z + c1 * w1.z + c2 * w2.z + cb.z;
                const float uw = c0 * w0.w + c1 * w1.w + c2 * w2.w + cb.w;

                st_nt4(out + (size_t)t * 512 + 256 + c,
                       (ux - mu2) * inv2 * g42.x + b42.x,
                       (uy - mu2) * inv2 * g42.y + b42.y,
                       (uz - mu2) * inv2 * g42.z + b42.z,
                       (uw - mu2) * inv2 * g42.w + b42.w);
            }
        }
        return;
    }

    const float* W0 = comb_W;
    const float* W1 = comb_W + 256 * 256;
    const float* W2 = comb_W + 512 * 256;
    const float* W3 = comb_W + 768 * 256;
    const float* W4 = comb_W + 1024 * 256;

    if (b < NB_TESTG) {
        // ============ graph+test fused path: 8 rows, 2-wave K-split ============
        const int row0 = b * 8;
        const int nr   = min(8, 1500 - row0);

        // stage graph rows: lds[0..4095] = G[8][512]
        for (int i = tid; i < 1024; i += 128) {
            const int r = i >> 7, m4 = (i & 127) * 4;
            const int rr = min(r, nr - 1);
            *reinterpret_cast<float4*>(&lds[r * 512 + m4]) =
                ld4(graph_tab + (size_t)(N_USER - 1 + row0 + rr) * 512 + m4);
        }
        __syncthreads();

        // phase B: tmp = G @ graph_W, wave k-slice [w*256, w*256+256)
        float4 acc[8];
        #pragma unroll
        for (int r = 0; r < 8; ++r) acc[r] = float4{0.f, 0.f, 0.f, 0.f};
        for (int m = w * 256; m < w * 256 + 256; m += 4) {
            const float4 wv0 = ld4(graph_W + (m + 0) * 256 + c);
            const float4 wv1 = ld4(graph_W + (m + 1) * 256 + c);
            const float4 wv2 = ld4(graph_W + (m + 2) * 256 + c);
            const float4 wv3 = ld4(graph_W + (m + 3) * 256 + c);
            #pragma unroll
            for (int r = 0; r < 8; ++r) {
                const float4 e = ld4(&lds[r * 512 + m]);
                acc[r].x += e.x * wv0.x + e.y * wv1.x + e.z * wv2.x + e.w * wv3.x;
                acc[r].y += e.x * wv0.y + e.y * wv1.y + e.z * wv2.y + e.w * wv3.y;
                acc[r].z += e.x * wv0.z + e.y * wv1.z + e.z * wv2.z + e.w * wv3.z;
                acc[r].w += e.x * wv0.w + e.y * wv1.w + e.z * wv2.w + e.w * wv3.w;
            }
        }
        __syncthreads();   // G reads done

        // reduce tmp into lds[4096..6143]
        if (w == 0) {
            #pragma unroll
            for (int r = 0; r < 8; ++r)
                *reinterpret_cast<float4*>(&lds[4096 + r * 256 + c]) = acc[r];
        }
        __syncthreads();
        if (w == 1) {
            #pragma unroll
            for (int r = 0; r < 8; ++r) {
                float4 t = ld4(&lds[4096 + r * 256 + c]);
                t.x += acc[r].x; t.y += acc[r].y; t.z += acc[r].z; t.w += acc[r].w;
                *reinterpret_cast<float4*>(&lds[4096 + r * 256 + c]) = t;
            }
        }
        // stage emb_test into lds[0..2047] (G region, dead after phase B barrier)
        for (int i = tid; i < 512; i += 128) {
            const int r = i >> 6, m4 = (i & 63) * 4;
            const int rr = min(r, nr - 1);
            *reinterpret_cast<float4*>(&lds[r * 256 + m4]) =
                ld4(emb_test + (size_t)(row0 + rr) * 256 + m4);
        }
        __syncthreads();

        // phase C: P = tmp @ W4 + test @ W1 + bias, wave k-slice [w*128, w*128+128)
        float4 acc2[8];
        float4 bacc = float4{0.f, 0.f, 0.f, 0.f};
        #pragma unroll
        for (int r = 0; r < 8; ++r) acc2[r] = float4{0.f, 0.f, 0.f, 0.f};
        for (int m = w * 128; m < w * 128 + 128; m += 4) {
            const float4 w40 = ld4(W4 + (m + 0) * 256 + c);
            const float4 w41 = ld4(W4 + (m + 1) * 256 + c);
            const float4 w42 = ld4(W4 + (m + 2) * 256 + c);
            const float4 w43 = ld4(W4 + (m + 3) * 256 + c);
            const float4 w10 = ld4(W1 + (m + 0) * 256 + c);
            const float4 w11 = ld4(W1 + (m + 1) * 256 + c);
            const float4 w12 = ld4(W1 + (m + 2) * 256 + c);
            const float4 w13 = ld4(W1 + (m + 3) * 256 + c);
            const float gb0 = graph_b[m + 0], gb1 = graph_b[m + 1];
            const float gb2 = graph_b[m + 2], gb3 = graph_b[m + 3];
            bacc.x += gb0 * w40.x + gb1 * w41.x + gb2 * w42.x + gb3 * w43.x;
            bacc.y += gb0 * w40.y + gb1 * w41.y + gb2 * w42.y + gb3 * w43.y;
            bacc.z += gb0 * w40.z + gb1 * w41.z + gb2 * w42.z + gb3 * w43.z;
            bacc.w += gb0 * w40.w + gb1 * w41.w + gb2 * w42.w + gb3 * w43.w;
            #pragma unroll
            for (int r = 0; r < 8; ++r) {
                const float4 tv = ld4(&lds[4096 + r * 256 + m]);
                const float4 ev = ld4(&lds[r * 256 + m]);
                acc2[r].x += tv.x * w40.x + tv.y * w41.x + tv.z * w42.x + tv.w * w43.x
                           + ev.x * w10.x + ev.y * w11.x + ev.z * w12.x + ev.w * w13.x;
                acc2[r].y += tv.x * w40.y + tv.y * w41.y + tv.z * w42.y + tv.w * w43.y
                           + ev.x * w10.y + ev.y * w11.y + ev.z * w12.y + ev.w * w13.y;
                acc2[r].z += tv.x * w40.z + tv.y * w41.z + tv.z * w42.z + tv.w * w43.z
                           + ev.x * w10.z + ev.y * w11.z + ev.z * w12.z + ev.w * w13.z;
                acc2[r].w += tv.x * w40.w + tv.y * w41.w + tv.z * w42.w + tv.w * w43.w
                           + ev.x * w10.w + ev.y * w11.w + ev.z * w12.w + ev.w * w13.w;
            }
        }
        // reduce acc2 -> lds[2048..4095], bacc -> lds[6144..6399]
        if (w == 0) {
            #pragma unroll
            for (int r = 0; r < 8; ++r)
                *reinterpret_cast<float4*>(&lds[2048 + r * 256 + c]) = acc2[r];
            *reinterpret_cast<float4*>(&lds[6144 + c]) = bacc;
        }
        __syncthreads();
        if (w == 1) {
            #pragma unroll
            for (int r = 0; r < 8; ++r) {
                float4 t = ld4(&lds[2048 + r * 256 + c]);
                t.x += acc2[r].x; t.y += acc2[r].y; t.z += acc2[r].z; t.w += acc2[r].w;
                *reinterpret_cast<float4*>(&lds[2048 + r * 256 + c]) = t;
            }
            float4 t = ld4(&lds[6144 + c]);
            t.x += bacc.x; t.y += bacc.y; t.z += bacc.z; t.w += bacc.w;
            *reinterpret_cast<float4*>(&lds[6144 + c]) = t;
        }
        __syncthreads();

        // final: wave w stores rows w*4 .. w*4+3
        const float4 cbv = ld4(comb_b + c);
        const float4 bb  = ld4(&lds[6144 + c]);
        #pragma unroll
        for (int r4 = 0; r4 < 4; ++r4) {
            const int r = w * 4 + r4;
            float4 o = ld4(&lds[2048 + r * 256 + c]);
            o.x += bb.x + cbv.x;
            o.y += bb.y + cbv.y;
            o.z += bb.z + cbv.z;
            o.w += bb.w + cbv.w;
            const float rs = wave_sum(rnd_bf(o.x) + rnd_bf(o.y) + rnd_bf(o.z) + rnd_bf(o.w));
            if (r < nr) {
                st_bf4(Ptestg + (size_t)(row0 + r) * 256 + c, o);
                if (lane == 0) Rtestg[row0 + r] = rs;
            }
        }
    } else {
        // ============ simple path: P = E @ W, 16 rows, 2-wave K-split ============
        const float* E; const float* W; bf16* P; float* R; int row0, Rn;
        const int sb = b - NB_TESTG;
        if (sb < NB_ITEM)               { E = emb_item; W = W2; P = Pitem; R = Ritem; row0 = sb * 16;             Rn = 9455; }
        else if (sb < NB_ITEM + NB_TAG) { E = emb_tag;  W = W3; P = Ptag;  R = Rtag;  row0 = (sb - NB_ITEM) * 16; Rn = 913;  }
        else                            { E = emb_int;  W = W0; P = Pint;  R = Rint;  row0 = 0;                   Rn = 3;    }
        const int nr = min(16, Rn - row0);

        // stage E rows: lds[0..4095] = E[16][256] (clamped)
        for (int i = tid; i < 1024; i += 128) {
            const int r = i >> 6, m4 = (i & 63) * 4;
            const int rr = min(r, nr - 1);
            *reinterpret_cast<float4*>(&lds[r * 256 + m4]) =
                ld4(E + (size_t)(row0 + rr) * 256 + m4);
        }
        __syncthreads();

        // wave k-slice [w*128, w*128+128)
        float4 acc[16];
        #pragma unroll
        for (int r = 0; r < 16; ++r) acc[r] = float4{0.f, 0.f, 0.f, 0.f};
        for (int m = w * 128; m < w * 128 + 128; m += 4) {
            const float4 wv0 = ld4(W + (m + 0) * 256 + c);
            const float4 wv1 = ld4(W + (m + 1) * 256 + c);
            const float4 wv2 = ld4(W + (m + 2) * 256 + c);
            const float4 wv3 = ld4(W + (m + 3) * 256 + c);
            #pragma unroll
            for (int r = 0; r < 16; ++r) {
                const float4 e = ld4(&lds[r * 256 + m]);
                acc[r].x += e.x * wv0.x + e.y * wv1.x + e.z * wv2.x + e.w * wv3.x;
                acc[r].y += e.x * wv0.y + e.y * wv1.y + e.z * wv2.y + e.w * wv3.y;
                acc[r].z += e.x * wv0.z + e.y * wv1.z + e.z * wv2.z + e.w * wv3.z;
                acc[r].w += e.x * wv0.w + e.y * wv1.w + e.z * wv2.w + e.w * wv3.w;
            }
        }
        __syncthreads();   // E reads done before overwrite

        if (w == 0) {
            #pragma unroll
            for (int r = 0; r < 16; ++r)
                *reinterpret_cast<float4*>(&lds[r * 256 + c]) = acc[r];
        }
        __syncthreads();
        if (w == 1) {
            #pragma unroll
            for (int r = 0; r < 16; ++r) {
                float4 t = ld4(&lds[r * 256 + c]);
                t.x += acc[r].x; t.y += acc[r].y; t.z += acc[r].z; t.w += acc[r].w;
                *reinterpret_cast<float4*>(&lds[r * 256 + c]) = t;
            }
        }
        __syncthreads();

        // store: wave w handles rows w*8 .. w*8+7
        #pragma unroll
        for (int r8 = 0; r8 < 8; ++r8) {
            const int r = w * 8 + r8;
            const float4 o = ld4(&lds[r * 256 + c]);
            const float rs = wave_sum(rnd_bf(o.x) + rnd_bf(o.y) + rnd_bf(o.z) + rnd_bf(o.w));
            if (r < nr) {
                st_bf4(P + (size_t)(row0 + r) * 256 + c, o);
                if (lane == 0) R[row0 + r] = rs;
            }
        }
    }
}

// Kernel B: cate half only. 8192 blocks x 4 waves x 4 tokens (round-13 proven form).
__global__ __launch_bounds__(256) void main_cate_kernel(
    const int* __restrict__ testId, const int* __restrict__ itemId,
    const int* __restrict__ tagId,  const int* __restrict__ inter,
    const bf16* __restrict__ Pint, const bf16* __restrict__ Ptestg,
    const bf16* __restrict__ Pitem, const bf16* __restrict__ Ptag,
    const float* __restrict__ Rint, const float* __restrict__ Rtestg,
    const float* __restrict__ Ritem, const float* __restrict__ Rtag,
    const float* __restrict__ comb_g, const float* __restrict__ comb_beta,
    float* __restrict__ out) {
    const int wid  = blockIdx.x * 4 + (threadIdx.x >> 6);
    const int lane = threadIdx.x & 63;
    const int c    = lane * 4;

    const float4 g4 = ld4(comb_g + c);
    const float4 b4 = ld4(comb_beta + c);
    const uint2 p0 = *reinterpret_cast<const uint2*>(Pint + 0 * 256 + c);
    const uint2 p1 = *reinterpret_cast<const uint2*>(Pint + 1 * 256 + c);
    const uint2 p2 = *reinterpret_cast<const uint2*>(Pint + 2 * 256 + c);
    const float ri0 = Rint[0], ri1 = Rint[1], ri2 = Rint[2];

    const int tb = wid * 4;
    const int4 tiv = *reinterpret_cast<const int4*>(testId + tb);
    const int4 iiv = *reinterpret_cast<const int4*>(itemId + tb);
    const int4 tgv = *reinterpret_cast<const int4*>(tagId  + tb);
    const int4 ivv = *reinterpret_cast<const int4*>(inter  + tb);
    const int tis[4] = {tiv.x, tiv.y, tiv.z, tiv.w};
    const int iis[4] = {iiv.x, iiv.y, iiv.z, iiv.w};
    const int tgs[4] = {tgv.x, tgv.y, tgv.z, tgv.w};
    const int ivs[4] = {ivv.x, ivv.y, ivv.z, ivv.w};

    uint2 gT[4], gI[4], gG[4];
    float sT[4], sI[4], sG[4];
    #pragma unroll
    for (int j = 0; j < 4; ++j) {
        gT[j] = *reinterpret_cast<const uint2*>(Ptestg + (size_t)tis[j] * 256 + c);
        gI[j] = *reinterpret_cast<const uint2*>(Pitem  + (size_t)iis[j] * 256 + c);
        gG[j] = *reinterpret_cast<const uint2*>(Ptag   + (size_t)tgs[j] * 256 + c);
        sT[j] = Rtestg[tis[j]];
        sI[j] = Ritem[iis[j]];
        sG[j] = Rtag[tgs[j]];
    }

    #pragma unroll
    for (int j = 0; j < 4; ++j) {
        const int t = tb + j;

        uint2 u0;
        u0.x = ivs[j] == 0 ? p0.x : (ivs[j] == 1 ? p1.x : p2.x);
        u0.y = ivs[j] == 0 ? p0.y : (ivs[j] == 1 ? p1.y : p2.y);
        const float sInt = ivs[j] == 0 ? ri0 : (ivs[j] == 1 ? ri1 : ri2);

        const float vx = bfl(u0.x) + bfl(gT[j].x) + bfl(gI[j].x) + bfl(gG[j].x);
        const float vy = bfh(u0.x) + bfh(gT[j].x) + bfh(gI[j].x) + bfh(gG[j].x);
        const float vz = bfl(u0.y) + bfl(gT[j].y) + bfl(gI[j].y) + bfl(gG[j].y);
        const float vw = bfh(u0.y) + bfh(gT[j].y) + bfh(gI[j].y) + bfh(gG[j].y);

        const float s   = sInt + sT[j] + sI[j] + sG[j];          // separable mean
        const float ss  = wave_sum(vx * vx + vy * vy + vz * vz + vw * vw);
        const float mu  = s * (1.f / 256.f);
        const float var = ss * (1.f / 256.f) - mu * mu;
        const float inv = rsqrtf(var + 1e-5f);

        st_nt4(out + (size_t)t * 512 + c,
               (vx - mu) * inv * g4.x + b4.x,
               (vy - mu) * inv * g4.y + b4.y,
               (vz - mu) * inv * g4.z + b4.z,
               (vw - mu) * inv * g4.w + b4.w);
    }
}

extern "C" void kernel_launch(void* const* d_in, const int* in_sizes, int n_in,
                              void* d_out, int out_size, void* d_ws, size_t ws_size,
                              hipStream_t stream) {
    const int*   testId     = (const int*)d_in[0];
    const int*   itemId     = (const int*)d_in[1];
    const int*   tagId      = (const int*)d_in[2];
    const float* cont_feats = (const float*)d_in[3];
    const int*   inter      = (const int*)d_in[4];
    const float* emb_int    = (const float*)d_in[5];
    const float* emb_test   = (const float*)d_in[6];
    const float* emb_item   = (const float*)d_in[7];
    const float* emb_tag    = (const float*)d_in[8];
    const float* graph_tab  = (const float*)d_in[9];
    const float* graph_W    = (const float*)d_in[10];
    const float* graph_b    = (const float*)d_in[11];
    const float* comb_W     = (const float*)d_in[12];
    const float* comb_b     = (const float*)d_in[13];
    const float* comb_g     = (const float*)d_in[14];
    const float* comb_beta  = (const float*)d_in[15];
    const float* cont_W     = (const float*)d_in[16];
    const float* cont_b     = (const float*)d_in[17];
    const float* cont_g     = (const float*)d_in[18];
    const float* cont_beta  = (const float*)d_in[19];
    float* out              = (float*)d_out;

    // Workspace: bf16 tables (~6.08 MB) then f32 row-sums (~48 KB).
    bf16* ws     = (bf16*)d_ws;
    bf16* Pitem  = ws;                         // 9455*256
    bf16* Ptestg = Pitem  + 9455 * 256;        // 1500*256
    bf16* Ptag   = Ptestg + 1500 * 256;        //  913*256
    bf16* Pint   = Ptag   +  913 * 256;        //    3*256
    float* Ritem  = (float*)(Pint + 3 * 256);  // 9455
    float* Rtestg = Ritem  + 9455;             // 1500
    float* Rtag   = Rtestg + 1500;             //  913
    float* Rint   = Rtag   +  913;             //    3

    precompute_cont_kernel<<<NB_A, 128, 0, stream>>>(
        emb_int, emb_test, emb_item, emb_tag, graph_tab, graph_W, graph_b,
        comb_W, comb_b, cont_feats, cont_W, cont_b, cont_g, cont_beta,
        Pint, Ptestg, Pitem, Ptag,
        Rint, Rtestg, Ritem, Rtag, out);

    main_cate_kernel<<<NTOK / (4 * 4), 256, 0, stream>>>(
        testId, itemId, tagId, inter,
        Pint, Ptestg, Pitem, Ptag,
        Rint, Rtestg, Ritem, Rtag,
        comb_g, comb_beta, out);
}